// Round 1
// baseline (252.836 us; speedup 1.0000x reference)
//
#include <hip/hip_runtime.h>
#include <hip/hip_bf16.h>
#include <hip/hip_fp16.h>

// Bahdanau attention: B=32, T=4096, QD=VD=AD=256
// out = (c [32,256], a [32,4096]) fp32, concatenated flat.

#define BB 32
#define TT 4096
#define DD 256

typedef _Float16 half8 __attribute__((ext_vector_type(8)));
typedef float f32x4 __attribute__((ext_vector_type(4)));
typedef float f32x16 __attribute__((ext_vector_type(16)));

// ---------------------------------------------------------------------------
// Kernel 0: prep.
//  blocks 0..31 : q-projection per batch  qp[b,a] = query[b,:].Wq[a,:] + bq[a] + bv[a]
//                 (bv folded in since tanh arg = (qdot+bq) + (kdot+bv))
//  blocks 32..63: Wv fp32 -> f16, pre-swizzled into MFMA B-fragment order:
//                 frag index o8 = ((sg*8 + nt)*64 + lane), holds 8 f16 (j=0..7)
//                 element: B[k][n] = Wv[n][k], k = sg*16 + (lane/32)*8 + j,
//                          n = nt*32 + (lane%32)
// ---------------------------------------------------------------------------
__global__ __launch_bounds__(256) void prep_kernel(
    const float* __restrict__ query, const float* __restrict__ Wq,
    const float* __restrict__ bq,    const float* __restrict__ Wv,
    const float* __restrict__ bv,
    float* __restrict__ qp, half8* __restrict__ wvfrag)
{
    int blk = blockIdx.x, tid = threadIdx.x;
    if (blk < BB) {
        __shared__ float ql[DD];
        ql[tid] = query[blk*DD + tid];
        __syncthreads();
        const f32x4* wr4 = (const f32x4*)(Wq + tid*DD);
        const f32x4* ql4 = (const f32x4*)ql;
        float s = 0.f;
        #pragma unroll 8
        for (int q = 0; q < DD/4; ++q) {
            f32x4 w4 = wr4[q];
            f32x4 x4 = ql4[q];
            s += w4[0]*x4[0] + w4[1]*x4[1] + w4[2]*x4[2] + w4[3]*x4[3];
        }
        qp[blk*DD + tid] = s + bq[tid] + bv[tid];
    } else {
        int o8 = (blk - BB)*256 + tid;      // 0..8191
        int L  = o8 & 63;
        int nt = (o8 >> 6) & 7;
        int sg = o8 >> 9;                   // 0..15
        int n  = nt*32 + (L & 31);
        int kb = sg*16 + (L >> 5)*8;
        const float* src = Wv + n*DD + kb;
        f32x4 s0 = *(const f32x4*)(src);
        f32x4 s1 = *(const f32x4*)(src + 4);
        half8 h;
        h[0]=(_Float16)s0[0]; h[1]=(_Float16)s0[1]; h[2]=(_Float16)s0[2]; h[3]=(_Float16)s0[3];
        h[4]=(_Float16)s1[0]; h[5]=(_Float16)s1[1]; h[6]=(_Float16)s1[2]; h[7]=(_Float16)s1[3];
        wvfrag[o8] = h;
    }
}

// ---------------------------------------------------------------------------
// Kernel 1: e-GEMM. 1024 blocks x 256 threads (4 waves).
// Block handles 128 rows (t) x full N=256 (a) x K=256 (v).
// A (values rows) read direct from global fp32 + cvt to f16 (each element used
// by exactly one wave). B (Wv frags) staged to LDS in frag order, 2 chunks of
// K=128 (64 KB LDS). Epilogue: e = sum_a wv[a]*tanh(qp[a] + key[a]) + bv0.
// ---------------------------------------------------------------------------
__device__ __forceinline__ float tanh_fast(float x) {
    float ex = __expf(2.f*x);
    return __builtin_fmaf(-2.f, __builtin_amdgcn_rcpf(ex + 1.f), 1.f);
}

__global__ __launch_bounds__(256, 2) void egemm_kernel(
    const float* __restrict__ values, const half8* __restrict__ wvfrag,
    const float* __restrict__ qp,     const float* __restrict__ wvs,
    const float* __restrict__ bvs,    float* __restrict__ e_out)
{
    __shared__ half8 Bl[8*8*64];     // 64 KB: [s in 0..7][nt in 0..7][lane]

    int tid = threadIdx.x;
    int w   = tid >> 6;
    int L   = tid & 63;
    int row0 = blockIdx.x * 128;     // global row base (row = b*TT + t)
    int b    = row0 >> 12;
    int m    = L & 31;
    int kh   = (L >> 5) * 8;         // k sub-offset within 16

    const float* arow = values + (size_t)(row0 + w*32 + m) * DD;

    f32x16 acc[8] = {};

    for (int c = 0; c < 2; ++c) {
        __syncthreads();
        // stage 64 KB of B frags (chunk c covers global k in [c*128, c*128+128))
        const half8* src = wvfrag + c*4096;
        #pragma unroll
        for (int i = 0; i < 16; ++i)
            Bl[i*256 + tid] = src[i*256 + tid];
        __syncthreads();

        #pragma unroll
        for (int s = 0; s < 8; ++s) {
            const float* ap = arow + c*128 + s*16 + kh;
            f32x4 a0 = *(const f32x4*)(ap);
            f32x4 a1 = *(const f32x4*)(ap + 4);
            half8 af;
            af[0]=(_Float16)a0[0]; af[1]=(_Float16)a0[1];
            af[2]=(_Float16)a0[2]; af[3]=(_Float16)a0[3];
            af[4]=(_Float16)a1[0]; af[5]=(_Float16)a1[1];
            af[6]=(_Float16)a1[2]; af[7]=(_Float16)a1[3];
            #pragma unroll
            for (int nt = 0; nt < 8; ++nt) {
                half8 bf = Bl[(s*8 + nt)*64 + L];
                acc[nt] = __builtin_amdgcn_mfma_f32_32x32x16_f16(af, bf, acc[nt], 0, 0, 0);
            }
        }
    }

    // epilogue: tanh + weighted reduction over a (= nt*32 + col)
    float q8[8], w8[8];
    #pragma unroll
    for (int nt = 0; nt < 8; ++nt) {
        q8[nt] = qp[b*DD + nt*32 + (L & 31)];
        w8[nt] = wvs[nt*32 + (L & 31)];
    }
    float part[16];
    #pragma unroll
    for (int r = 0; r < 16; ++r) part[r] = 0.f;
    #pragma unroll
    for (int nt = 0; nt < 8; ++nt) {
        #pragma unroll
        for (int r = 0; r < 16; ++r) {
            float x = acc[nt][r] + q8[nt];
            part[r] += tanh_fast(x) * w8[nt];
        }
    }
    // each row's partial lives in the 32 lanes of one half; butterfly-reduce
    #pragma unroll
    for (int r = 0; r < 16; ++r) {
        part[r] += __shfl_xor(part[r], 1);
        part[r] += __shfl_xor(part[r], 2);
        part[r] += __shfl_xor(part[r], 4);
        part[r] += __shfl_xor(part[r], 8);
        part[r] += __shfl_xor(part[r], 16);
    }
    int r = L & 31;
    if (r < 16) {
        int rowi = (r & 3) + 8*(r >> 2) + 4*(L >> 5);   // C/D row mapping
        e_out[row0 + w*32 + rowi] = part[r] + bvs[0];
    }
}

// ---------------------------------------------------------------------------
// Kernel 2: softmax over T per batch. 32 blocks x 256 threads, in-place on the
// a-region of d_out (which currently holds e).
// ---------------------------------------------------------------------------
__global__ __launch_bounds__(256) void softmax_kernel(float* __restrict__ ea)
{
    int bidx = blockIdx.x, tid = threadIdx.x;
    int wv = tid >> 6, lane = tid & 63;
    float* rowp = ea + bidx*TT;
    f32x4 v[4];
    #pragma unroll
    for (int i = 0; i < 4; ++i)
        v[i] = *(const f32x4*)(rowp + (i*256 + tid)*4);

    float m = -INFINITY;
    #pragma unroll
    for (int i = 0; i < 4; ++i)
        #pragma unroll
        for (int j = 0; j < 4; ++j) m = fmaxf(m, v[i][j]);
    m = fmaxf(m, __shfl_xor(m, 1));
    m = fmaxf(m, __shfl_xor(m, 2));
    m = fmaxf(m, __shfl_xor(m, 4));
    m = fmaxf(m, __shfl_xor(m, 8));
    m = fmaxf(m, __shfl_xor(m, 16));
    m = fmaxf(m, __shfl_xor(m, 32));
    __shared__ float red[4];
    if (lane == 0) red[wv] = m;
    __syncthreads();
    m = fmaxf(fmaxf(red[0], red[1]), fmaxf(red[2], red[3]));

    float sum = 0.f;
    #pragma unroll
    for (int i = 0; i < 4; ++i)
        #pragma unroll
        for (int j = 0; j < 4; ++j) {
            v[i][j] = __expf(v[i][j] - m);
            sum += v[i][j];
        }
    sum += __shfl_xor(sum, 1);
    sum += __shfl_xor(sum, 2);
    sum += __shfl_xor(sum, 4);
    sum += __shfl_xor(sum, 8);
    sum += __shfl_xor(sum, 16);
    sum += __shfl_xor(sum, 32);
    __syncthreads();
    if (lane == 0) red[wv] = sum;
    __syncthreads();
    sum = red[0] + red[1] + red[2] + red[3];
    float inv = 1.f / sum;

    #pragma unroll
    for (int i = 0; i < 4; ++i) {
        f32x4 o = v[i];
        o[0]*=inv; o[1]*=inv; o[2]*=inv; o[3]*=inv;
        *(f32x4*)(rowp + (i*256 + tid)*4) = o;
    }
}

// ---------------------------------------------------------------------------
// Kernel 3: context c[b,v] = sum_t a[b,t] * values[b,t,v].
// 512 blocks (32 b x 16 t-chunks of 256) x 256 threads.
// wave w handles t = w mod 4 stripe; lane holds one float4 column group.
// ---------------------------------------------------------------------------
__global__ __launch_bounds__(256) void ctx_kernel(
    const float* __restrict__ values, const float* __restrict__ a,
    float* __restrict__ cout)
{
    int blk = blockIdx.x;
    int b = blk >> 4, chunk = blk & 15;
    int tid = threadIdx.x;
    int tsub = tid >> 6;           // wave id = t stripe
    int vg = tid & 63;             // float4 column group
    const float* ab = a + b*TT + chunk*256;
    const float* vb = values + ((size_t)b*TT + chunk*256)*DD + vg*4;
    f32x4 csum = {};
    #pragma unroll 4
    for (int i = 0; i < 64; ++i) {
        int t = tsub + i*4;
        float at = ab[t];
        f32x4 vv = *(const f32x4*)(vb + (size_t)t*DD);
        csum[0] += at*vv[0]; csum[1] += at*vv[1];
        csum[2] += at*vv[2]; csum[3] += at*vv[3];
    }
    __shared__ f32x4 red[4][64];
    red[tsub][vg] = csum;
    __syncthreads();
    if (tsub == 0) {
        f32x4 tot = red[0][vg];
        f32x4 t1 = red[1][vg], t2 = red[2][vg], t3 = red[3][vg];
        tot[0]+=t1[0]+t2[0]+t3[0]; tot[1]+=t1[1]+t2[1]+t3[1];
        tot[2]+=t1[2]+t2[2]+t3[2]; tot[3]+=t1[3]+t2[3]+t3[3];
        #pragma unroll
        for (int j = 0; j < 4; ++j)
            atomicAdd(&cout[b*DD + vg*4 + j], tot[j]);
    }
}

// ---------------------------------------------------------------------------
extern "C" void kernel_launch(void* const* d_in, const int* in_sizes, int n_in,
                              void* d_out, int out_size, void* d_ws, size_t ws_size,
                              hipStream_t stream)
{
    (void)in_sizes; (void)n_in; (void)out_size; (void)ws_size;
    const float* query  = (const float*)d_in[0];
    const float* values = (const float*)d_in[1];
    const float* Wq     = (const float*)d_in[2];
    const float* bq     = (const float*)d_in[3];
    const float* Wv     = (const float*)d_in[4];
    const float* bv     = (const float*)d_in[5];
    const float* wvs    = (const float*)d_in[6];
    const float* bvs    = (const float*)d_in[7];

    float* out  = (float*)d_out;
    float* cptr = out;             // [32,256]
    float* aptr = out + BB*DD;     // [32,4096] (holds e, then a in-place)

    float* qp      = (float*)d_ws;                       // 8192 f32 = 32 KB
    half8* wvfrag  = (half8*)((char*)d_ws + BB*DD*4);    // 128 KB

    hipMemsetAsync(cptr, 0, BB*DD*sizeof(float), stream);
    prep_kernel<<<64, 256, 0, stream>>>(query, Wq, bq, Wv, bv, qp, wvfrag);
    egemm_kernel<<<1024, 256, 0, stream>>>(values, wvfrag, qp, wvs, bvs, aptr);
    softmax_kernel<<<BB, 256, 0, stream>>>(aptr);
    ctx_kernel<<<512, 256, 0, stream>>>(values, aptr, cptr);
}